// Round 9
// baseline (182.444 us; speedup 1.0000x reference)
//
#include <hip/hip_runtime.h>

// MGN_NET: 3x NNConv(mean) + ReLU, then pairwise-L1 CBT [35x35]. All fp32.
// R8 -> R9: revert the closer-election fusion (60 us anomaly; third data
// point that intra-kernel cross-block signaling is 10s-of-us expensive on
// this chip). Back to R7's plain dispatch chain (measured best, 126 us),
// minus one dispatch: x3+cbt fuse into ONE single-block kernel (legal
// without any signaling -- one block sees all 35 nodes).
//   x1_k   (145 blk): edge lists + deg -> ws; x1 slices; zero agg3
//   x2_k   (560 blk = 35n x 16og): x2[n, 16-o] end-to-end (R7 verbatim)
//   p3_k   (280 blk = 35n x 8iq): layer-3 i-quarter partials -> agg3 atomics
//   x3cbt_k (1 blk): x3 all nodes (lin3 k-loop inverted, wave=o3-lane,
//          broadcast LDS x2 reads, static accumulators) + CBT -> out
// All cross-kernel data uses plain cached ld/st: kernel boundaries provide
// device-wide ordering + coherence.

#define NN 35
#define NE 1190
#define MAXE 80

// float offsets into ws
#define OFF_CNT  0       // 35
#define OFF_EL   64      // ints, 35*80 = 2800 -> ends 2864
#define OFF_X1   2944    // 8960 -> 11904
#define OFF_X2   11904   // 8960 -> 20864
#define OFF_AGG3 23168   // 2240 -> 25408

// ---------------- K1: edge lists + x1 slices + zero agg3 -------------------
__global__ __launch_bounds__(512) void x1_k(
    float* __restrict__ ws, const float* __restrict__ x,
    const float* __restrict__ ea, const int* __restrict__ ei,
    const float* __restrict__ w1, const float* __restrict__ b1w,
    const float* __restrict__ lin1, const float* __restrict__ b1) {
    __shared__ int elistS[MAXE];
    __shared__ int ecntS;
    __shared__ float partS[8 * 64];
    const int tid = threadIdx.x, bid = blockIdx.x;
    if (bid >= 140) {
        const int idx = (bid - 140) * 512 + tid;
        if (idx < NN * 64) ws[OFF_AGG3 + idx] = 0.f;
        return;
    }
    const int n = bid >> 2, och = bid & 3;
    if (tid == 0) ecntS = 0;
    __syncthreads();
    for (int e = tid; e < NE; e += 512) {
        if (ei[NE + e] == n) {
            const int p = atomicAdd(&ecntS, 1);
            if (p < MAXE) elistS[p] = e;
        }
    }
    __syncthreads();
    const int deg = ecntS;
    const int dl = deg < MAXE ? deg : MAXE;
    const int ol = tid & 63, ech = tid >> 6;
    const int o = och * 64 + ol;
    const float2* wr = (const float2*)(w1 + o * 6);
    const float2 wv0 = wr[0], wv1 = wr[1], wv2 = wr[2];
    const float bb = b1w[o];
    float a = 0.f;
    for (int k = ech; k < dl; k += 8) {
        const int e = elistS[k];
        const float2* eap = (const float2*)(ea + e * 6);
        const float2 a0 = eap[0], a1 = eap[1], a2 = eap[2];
        float d = bb;
        d = fmaf(a0.x, wv0.x, d); d = fmaf(a0.y, wv0.y, d);
        d = fmaf(a1.x, wv1.x, d); d = fmaf(a1.y, wv1.y, d);
        d = fmaf(a2.x, wv2.x, d); d = fmaf(a2.y, wv2.y, d);
        a = fmaf(x[ei[e]], fmaxf(d, 0.f), a);
    }
    partS[ech * 64 + ol] = a;
    __syncthreads();
    if (ech == 0) {
        float s = a;
#pragma unroll
        for (int p = 1; p < 8; p++) s += partS[p * 64 + ol];
        const float c = fmaxf((float)deg, 1.f);
        ws[OFF_X1 + n * 256 + o] = fmaxf(s / c + x[n] * lin1[o] + b1[o], 0.f);
    }
    if (och == 0) {
        if (tid < dl) ((int*)(ws + OFF_EL))[n * MAXE + tid] = elistS[tid];
        if (tid == 0) ws[OFF_CNT + n] = (float)deg;
    }
}

// ---------------- K2: dst-centric layer 2 -> x2[n, 16-o slice] -------------
__global__ __launch_bounds__(512) void x2_k(
    float* __restrict__ ws, const float* __restrict__ ea,
    const int* __restrict__ ei, const float* __restrict__ w2,
    const float* __restrict__ b2w, const float* __restrict__ lin2,
    const float* __restrict__ b2) {
    __shared__ float smem[11264];          // 45 KiB -> 3 blocks/CU
    float* xsS = smem;                     // 80*128 = 10240
    float* x1S = smem + 10240;             // 256
    float* easS = smem + 10496;            // 480
    int* srcS = (int*)(smem + 10976);      // 80
    int* elS = (int*)(smem + 11056);       // 80
    float* partA = smem;                   // alias xsS (used after compute)
    float* partB = smem + 512;
    __shared__ float cS;
    const int tid = threadIdx.x;
    const int n = blockIdx.x >> 4, og = blockIdx.x & 15;
    const int ol = tid & 15, ic = tid >> 4;   // 16 o-lanes x 32 i-chunks(4)
    const int o = og * 16 + ol;
    if (tid == 0) cS = ws[OFF_CNT + n];
    if (tid < MAXE) elS[tid] = ((const int*)(ws + OFF_EL))[n * MAXE + tid];
    if (tid >= 448) {
        const int q = tid - 448;
        *(float4*)&x1S[q * 4] = *(const float4*)(ws + OFF_X1 + n * 256 + q * 4);
    }
    __syncthreads();
    const int deg = (int)cS;
    const int dl = deg < MAXE ? deg : MAXE;
    if (tid < dl) {
        const int eid = elS[tid];
        srcS[tid] = ei[eid];
        const float2* eap = (const float2*)(ea + eid * 6);
        *(float2*)&easS[tid * 6] = eap[0];
        *(float2*)&easS[tid * 6 + 2] = eap[1];
        *(float2*)&easS[tid * 6 + 4] = eap[2];
    }
    float accm = 0.f;
    for (int p = 0; p < 2; ++p) {          // i-halves of 128
        __syncthreads();                   // srcS/easS ready; xs reusable
        for (int idx = tid; idx < dl * 32; idx += 512) {
            const int e = idx >> 5, ip = (idx & 31) * 4;
            *(float4*)&xsS[e * 128 + ip] =
                *(const float4*)(ws + OFF_X1 + srcS[e] * 256 + p * 128 + ip);
        }
        __syncthreads();
        const int i0 = p * 128 + ic * 4;
        const float* wp0 = w2 + (size_t)((i0 + 0) * 256 + o) * 6;
        const float* wp1 = w2 + (size_t)((i0 + 1) * 256 + o) * 6;
        const float* wp2 = w2 + (size_t)((i0 + 2) * 256 + o) * 6;
        const float* wp3 = w2 + (size_t)((i0 + 3) * 256 + o) * 6;
        const float2 wa0 = *(const float2*)wp0;
        const float2 wb0 = *(const float2*)(wp0 + 2);
        const float2 wc0 = *(const float2*)(wp0 + 4);
        const float2 wa1 = *(const float2*)wp1;
        const float2 wb1 = *(const float2*)(wp1 + 2);
        const float2 wc1 = *(const float2*)(wp1 + 4);
        const float2 wa2 = *(const float2*)wp2;
        const float2 wb2 = *(const float2*)(wp2 + 2);
        const float2 wc2 = *(const float2*)(wp2 + 4);
        const float2 wa3 = *(const float2*)wp3;
        const float2 wb3 = *(const float2*)(wp3 + 2);
        const float2 wc3 = *(const float2*)(wp3 + 4);
        const float bb0 = b2w[(i0 + 0) * 256 + o];
        const float bb1 = b2w[(i0 + 1) * 256 + o];
        const float bb2 = b2w[(i0 + 2) * 256 + o];
        const float bb3 = b2w[(i0 + 3) * 256 + o];
        for (int e = 0; e < dl; ++e) {
            const float2 e01 = *(const float2*)&easS[e * 6];
            const float2 e23 = *(const float2*)&easS[e * 6 + 2];
            const float2 e45 = *(const float2*)&easS[e * 6 + 4];
            const float4 xv = *(const float4*)&xsS[e * 128 + ic * 4];
            float d0 = bb0, d1 = bb1, d2 = bb2, d3 = bb3;
            d0 = fmaf(e01.x, wa0.x, d0); d1 = fmaf(e01.x, wa1.x, d1);
            d2 = fmaf(e01.x, wa2.x, d2); d3 = fmaf(e01.x, wa3.x, d3);
            d0 = fmaf(e01.y, wa0.y, d0); d1 = fmaf(e01.y, wa1.y, d1);
            d2 = fmaf(e01.y, wa2.y, d2); d3 = fmaf(e01.y, wa3.y, d3);
            d0 = fmaf(e23.x, wb0.x, d0); d1 = fmaf(e23.x, wb1.x, d1);
            d2 = fmaf(e23.x, wb2.x, d2); d3 = fmaf(e23.x, wb3.x, d3);
            d0 = fmaf(e23.y, wb0.y, d0); d1 = fmaf(e23.y, wb1.y, d1);
            d2 = fmaf(e23.y, wb2.y, d2); d3 = fmaf(e23.y, wb3.y, d3);
            d0 = fmaf(e45.x, wc0.x, d0); d1 = fmaf(e45.x, wc1.x, d1);
            d2 = fmaf(e45.x, wc2.x, d2); d3 = fmaf(e45.x, wc3.x, d3);
            d0 = fmaf(e45.y, wc0.y, d0); d1 = fmaf(e45.y, wc1.y, d1);
            d2 = fmaf(e45.y, wc2.y, d2); d3 = fmaf(e45.y, wc3.y, d3);
            d0 = fmaxf(d0, 0.f); d1 = fmaxf(d1, 0.f);
            d2 = fmaxf(d2, 0.f); d3 = fmaxf(d3, 0.f);
            accm = fmaf(xv.x, d0, accm);
            accm = fmaf(xv.y, d1, accm);
            accm = fmaf(xv.z, d2, accm);
            accm = fmaf(xv.w, d3, accm);
        }
    }
    // root (lin2) partial over this thread's 8 i's
    float accl = 0.f;
    {
        const float4 l0 = *(const float4*)(lin2 + (size_t)o * 256 + ic * 4);
        const float4 xa = *(const float4*)&x1S[ic * 4];
        accl = fmaf(l0.x, xa.x, accl); accl = fmaf(l0.y, xa.y, accl);
        accl = fmaf(l0.z, xa.z, accl); accl = fmaf(l0.w, xa.w, accl);
        const float4 l1 = *(const float4*)(lin2 + (size_t)o * 256 + 128 + ic * 4);
        const float4 xb = *(const float4*)&x1S[128 + ic * 4];
        accl = fmaf(l1.x, xb.x, accl); accl = fmaf(l1.y, xb.y, accl);
        accl = fmaf(l1.z, xb.z, accl); accl = fmaf(l1.w, xb.w, accl);
    }
    __syncthreads();                 // all xs reads done; partA aliases xsS
    partA[ic * 16 + ol] = accm;
    partB[ic * 16 + ol] = accl;
    __syncthreads();
    if (tid < 16) {
        float m = 0.f, l = 0.f;
        for (int k = 0; k < 32; ++k) {
            m += partA[k * 16 + tid];
            l += partB[k * 16 + tid];
        }
        const float c = fmaxf(cS, 1.f);
        ws[OFF_X2 + n * 256 + og * 16 + tid] =
            fmaxf(m / c + l + b2[og * 16 + tid], 0.f);
    }
}

// ---------------- K3: layer-3 i-quarter partials -> agg3 -------------------
__global__ __launch_bounds__(512) void p3_k(
    float* __restrict__ ws, const float* __restrict__ ea,
    const int* __restrict__ ei, const float* __restrict__ w3,
    const float* __restrict__ b3w) {
    __shared__ float xsS[MAXE * 32];       // 2560
    __shared__ float easS[MAXE * 6];       // 480
    __shared__ int srcS[MAXE];
    __shared__ int elS[MAXE];
    __shared__ float partS[8 * 64];
    __shared__ float cS;
    const int tid = threadIdx.x;
    const int n = blockIdx.x >> 3, iq = blockIdx.x & 7;
    const int i0 = iq * 32;
    const int ol = tid & 63, ic = tid >> 6;   // 64 o-lanes x 8 i-chunks(4)
    if (tid == 0) cS = ws[OFF_CNT + n];
    if (tid < MAXE) elS[tid] = ((const int*)(ws + OFF_EL))[n * MAXE + tid];
    __syncthreads();
    const int deg = (int)cS;
    const int dl = deg < MAXE ? deg : MAXE;
    if (tid < dl) {
        const int eid = elS[tid];
        srcS[tid] = ei[eid];
        const float2* eap = (const float2*)(ea + eid * 6);
        *(float2*)&easS[tid * 6] = eap[0];
        *(float2*)&easS[tid * 6 + 2] = eap[1];
        *(float2*)&easS[tid * 6 + 4] = eap[2];
    }
    __syncthreads();
    for (int idx = tid; idx < dl * 8; idx += 512) {
        const int e = idx >> 3, ip = (idx & 7) * 4;
        *(float4*)&xsS[e * 32 + ip] =
            *(const float4*)(ws + OFF_X2 + srcS[e] * 256 + i0 + ip);
    }
    __syncthreads();
    const int ib = i0 + ic * 4;
    const float* wp0 = w3 + (size_t)((ib + 0) * 64 + ol) * 6;
    const float* wp1 = w3 + (size_t)((ib + 1) * 64 + ol) * 6;
    const float* wp2 = w3 + (size_t)((ib + 2) * 64 + ol) * 6;
    const float* wp3 = w3 + (size_t)((ib + 3) * 64 + ol) * 6;
    const float2 wa0 = *(const float2*)wp0;
    const float2 wb0 = *(const float2*)(wp0 + 2);
    const float2 wc0 = *(const float2*)(wp0 + 4);
    const float2 wa1 = *(const float2*)wp1;
    const float2 wb1 = *(const float2*)(wp1 + 2);
    const float2 wc1 = *(const float2*)(wp1 + 4);
    const float2 wa2 = *(const float2*)wp2;
    const float2 wb2 = *(const float2*)(wp2 + 2);
    const float2 wc2 = *(const float2*)(wp2 + 4);
    const float2 wa3 = *(const float2*)wp3;
    const float2 wb3 = *(const float2*)(wp3 + 2);
    const float2 wc3 = *(const float2*)(wp3 + 4);
    const float bb0 = b3w[(ib + 0) * 64 + ol];
    const float bb1 = b3w[(ib + 1) * 64 + ol];
    const float bb2 = b3w[(ib + 2) * 64 + ol];
    const float bb3 = b3w[(ib + 3) * 64 + ol];
    float accm = 0.f;
    for (int e = 0; e < dl; ++e) {
        const float2 e01 = *(const float2*)&easS[e * 6];
        const float2 e23 = *(const float2*)&easS[e * 6 + 2];
        const float2 e45 = *(const float2*)&easS[e * 6 + 4];
        const float4 xv = *(const float4*)&xsS[e * 32 + ic * 4];
        float d0 = bb0, d1 = bb1, d2 = bb2, d3 = bb3;
        d0 = fmaf(e01.x, wa0.x, d0); d1 = fmaf(e01.x, wa1.x, d1);
        d2 = fmaf(e01.x, wa2.x, d2); d3 = fmaf(e01.x, wa3.x, d3);
        d0 = fmaf(e01.y, wa0.y, d0); d1 = fmaf(e01.y, wa1.y, d1);
        d2 = fmaf(e01.y, wa2.y, d2); d3 = fmaf(e01.y, wa3.y, d3);
        d0 = fmaf(e23.x, wb0.x, d0); d1 = fmaf(e23.x, wb1.x, d1);
        d2 = fmaf(e23.x, wb2.x, d2); d3 = fmaf(e23.x, wb3.x, d3);
        d0 = fmaf(e23.y, wb0.y, d0); d1 = fmaf(e23.y, wb1.y, d1);
        d2 = fmaf(e23.y, wb2.y, d2); d3 = fmaf(e23.y, wb3.y, d3);
        d0 = fmaf(e45.x, wc0.x, d0); d1 = fmaf(e45.x, wc1.x, d1);
        d2 = fmaf(e45.x, wc2.x, d2); d3 = fmaf(e45.x, wc3.x, d3);
        d0 = fmaf(e45.y, wc0.y, d0); d1 = fmaf(e45.y, wc1.y, d1);
        d2 = fmaf(e45.y, wc2.y, d2); d3 = fmaf(e45.y, wc3.y, d3);
        d0 = fmaxf(d0, 0.f); d1 = fmaxf(d1, 0.f);
        d2 = fmaxf(d2, 0.f); d3 = fmaxf(d3, 0.f);
        accm = fmaf(xv.x, d0, accm);
        accm = fmaf(xv.y, d1, accm);
        accm = fmaf(xv.z, d2, accm);
        accm = fmaf(xv.w, d3, accm);
    }
    partS[ic * 64 + ol] = accm;
    __syncthreads();
    if (ic == 0) {
        float s = accm;
#pragma unroll
        for (int p = 1; p < 8; ++p) s += partS[p * 64 + ol];
        atomicAdd(ws + OFF_AGG3 + n * 64 + ol, s);
    }
}

// ---------- K4: single-block x3 (all nodes) + CBT -> out -------------------
// One block sees everything: no cross-block signaling needed. Wave w owns
// o3-lane = tid&63 and nodes n in {w, w+8, ...}; lin3 row read once per
// thread; x2 LDS reads are wave-uniform broadcasts (conflict-free).
__global__ __launch_bounds__(512) void x3cbt_k(
    const float* __restrict__ ws, const float* __restrict__ lin3,
    const float* __restrict__ b3, float* __restrict__ out) {
    __shared__ float x2S[NN * 256];   // 35840 B
    __shared__ float x3S[NN * 64];    // 8960 B
    const int tid = threadIdx.x;
    for (int idx = tid; idx < NN * 64; idx += 512)
        *(float4*)&x2S[idx * 4] = *(const float4*)(ws + OFF_X2 + idx * 4);
    __syncthreads();
    const int o3 = tid & 63, w = tid >> 6;  // 8 waves
    {
        const float4* l4 = (const float4*)(lin3 + (size_t)o3 * 256);
        float a0 = 0.f, a1 = 0.f, a2 = 0.f, a3 = 0.f, a4 = 0.f;
        const bool has4 = (w + 32) < NN;  // wave-uniform
        for (int k = 0; k < 64; ++k) {
            const float4 wv = l4[k];
            {
                const float4 xv = *(const float4*)&x2S[w * 256 + k * 4];
                a0 = fmaf(wv.x, xv.x, a0); a0 = fmaf(wv.y, xv.y, a0);
                a0 = fmaf(wv.z, xv.z, a0); a0 = fmaf(wv.w, xv.w, a0);
            }
            {
                const float4 xv = *(const float4*)&x2S[(w + 8) * 256 + k * 4];
                a1 = fmaf(wv.x, xv.x, a1); a1 = fmaf(wv.y, xv.y, a1);
                a1 = fmaf(wv.z, xv.z, a1); a1 = fmaf(wv.w, xv.w, a1);
            }
            {
                const float4 xv = *(const float4*)&x2S[(w + 16) * 256 + k * 4];
                a2 = fmaf(wv.x, xv.x, a2); a2 = fmaf(wv.y, xv.y, a2);
                a2 = fmaf(wv.z, xv.z, a2); a2 = fmaf(wv.w, xv.w, a2);
            }
            {
                const float4 xv = *(const float4*)&x2S[(w + 24) * 256 + k * 4];
                a3 = fmaf(wv.x, xv.x, a3); a3 = fmaf(wv.y, xv.y, a3);
                a3 = fmaf(wv.z, xv.z, a3); a3 = fmaf(wv.w, xv.w, a3);
            }
            if (has4) {
                const float4 xv = *(const float4*)&x2S[(w + 32) * 256 + k * 4];
                a4 = fmaf(wv.x, xv.x, a4); a4 = fmaf(wv.y, xv.y, a4);
                a4 = fmaf(wv.z, xv.z, a4); a4 = fmaf(wv.w, xv.w, a4);
            }
        }
        const float bb = b3[o3];
        {
            const int n = w;
            const float c = fmaxf(ws[OFF_CNT + n], 1.f);
            x3S[n * 64 + o3] =
                fmaxf(ws[OFF_AGG3 + n * 64 + o3] / c + a0 + bb, 0.f);
        }
        {
            const int n = w + 8;
            const float c = fmaxf(ws[OFF_CNT + n], 1.f);
            x3S[n * 64 + o3] =
                fmaxf(ws[OFF_AGG3 + n * 64 + o3] / c + a1 + bb, 0.f);
        }
        {
            const int n = w + 16;
            const float c = fmaxf(ws[OFF_CNT + n], 1.f);
            x3S[n * 64 + o3] =
                fmaxf(ws[OFF_AGG3 + n * 64 + o3] / c + a2 + bb, 0.f);
        }
        {
            const int n = w + 24;
            const float c = fmaxf(ws[OFF_CNT + n], 1.f);
            x3S[n * 64 + o3] =
                fmaxf(ws[OFF_AGG3 + n * 64 + o3] / c + a3 + bb, 0.f);
        }
        if (has4) {
            const int n = w + 32;
            const float c = fmaxf(ws[OFF_CNT + n], 1.f);
            x3S[n * 64 + o3] =
                fmaxf(ws[OFF_AGG3 + n * 64 + o3] / c + a4 + bb, 0.f);
        }
    }
    __syncthreads();
    // CBT: wave w handles rows i; lanes reduce over the 64 features
    for (int i = 0; i < NN; ++i) {
        const float xi = x3S[i * 64 + o3];
        for (int j = w; j < NN; j += 8) {
            float d = fabsf(xi - x3S[j * 64 + o3]);
#pragma unroll
            for (int off = 32; off > 0; off >>= 1) d += __shfl_xor(d, off);
            if (o3 == 0) out[i * NN + j] = d;
        }
    }
}

extern "C" void kernel_launch(void* const* d_in, const int* in_sizes, int n_in,
                              void* d_out, int out_size, void* d_ws, size_t ws_size,
                              hipStream_t stream) {
    (void)in_sizes; (void)n_in; (void)out_size; (void)ws_size;
    const float* x    = (const float*)d_in[0];
    const float* ea   = (const float*)d_in[1];
    const int*   ei   = (const int*)d_in[2];
    const float* nn1w = (const float*)d_in[3];
    const float* nn1b = (const float*)d_in[4];
    const float* lin1 = (const float*)d_in[5];
    const float* b1   = (const float*)d_in[6];
    const float* nn2w = (const float*)d_in[7];
    const float* nn2b = (const float*)d_in[8];
    const float* lin2 = (const float*)d_in[9];
    const float* b2   = (const float*)d_in[10];
    const float* nn3w = (const float*)d_in[11];
    const float* nn3b = (const float*)d_in[12];
    const float* lin3 = (const float*)d_in[13];
    const float* b3   = (const float*)d_in[14];

    float* ws = (float*)d_ws;
    x1_k<<<145, 512, 0, stream>>>(ws, x, ea, ei, nn1w, nn1b, lin1, b1);
    x2_k<<<NN * 16, 512, 0, stream>>>(ws, ea, ei, nn2w, nn2b, lin2, b2);
    p3_k<<<NN * 8, 512, 0, stream>>>(ws, ea, ei, nn3w, nn3b);
    x3cbt_k<<<1, 512, 0, stream>>>(ws, lin3, b3, (float*)d_out);
}

// Round 10
// 126.940 us; speedup vs baseline: 1.4373x; 1.4373x over previous
//
#include <hip/hip_runtime.h>

// MGN_NET: 3x NNConv(mean) + ReLU, then pairwise-L1 CBT [35x35]. All fp32.
// R9 -> R10: drop the single-block fusion (measured: 1-block kernels pay
// ~60 us of un-hidden cold-memory latency on one CU). Keep R7's plain
// dispatch chain but merge layer-3 aggregation+output the SAFE way: a
// dst-centric (node, 16-o slice) block computes x3 end-to-end (clone of the
// proven x2_k skeleton) -- no atomics, no agg3, no zeroing, no signaling.
//   x1_k   (140 blk = 35n x 4og): edge lists + deg -> ws; x1 slices
//   x2_k   (560 blk = 35n x 16og): x2[n, 16-o] end-to-end (R7 verbatim)
//   p3x3_k (140 blk = 35n x 4og): x3[n, 16-o] end-to-end (x2_k clone, w3/lin3)
//   cbt_k  (35 blk): pairwise-L1 CBT -> out
// All cross-kernel data uses plain cached ld/st; kernel boundaries provide
// device-wide ordering + coherence.

#define NN 35
#define NE 1190
#define MAXE 80

// float offsets into ws
#define OFF_CNT  0       // 35
#define OFF_EL   64      // ints, 35*80 = 2800 -> ends 2864
#define OFF_X1   2944    // 8960 -> 11904
#define OFF_X2   11904   // 8960 -> 20864
#define OFF_X3   20864   // 2240 -> 23104

// ---------------- K1: edge lists + x1 slices -------------------------------
__global__ __launch_bounds__(512) void x1_k(
    float* __restrict__ ws, const float* __restrict__ x,
    const float* __restrict__ ea, const int* __restrict__ ei,
    const float* __restrict__ w1, const float* __restrict__ b1w,
    const float* __restrict__ lin1, const float* __restrict__ b1) {
    __shared__ int elistS[MAXE];
    __shared__ int ecntS;
    __shared__ float partS[8 * 64];
    const int tid = threadIdx.x, bid = blockIdx.x;
    const int n = bid >> 2, och = bid & 3;
    if (tid == 0) ecntS = 0;
    __syncthreads();
    for (int e = tid; e < NE; e += 512) {
        if (ei[NE + e] == n) {
            const int p = atomicAdd(&ecntS, 1);
            if (p < MAXE) elistS[p] = e;
        }
    }
    __syncthreads();
    const int deg = ecntS;
    const int dl = deg < MAXE ? deg : MAXE;
    const int ol = tid & 63, ech = tid >> 6;
    const int o = och * 64 + ol;
    const float2* wr = (const float2*)(w1 + o * 6);
    const float2 wv0 = wr[0], wv1 = wr[1], wv2 = wr[2];
    const float bb = b1w[o];
    float a = 0.f;
    for (int k = ech; k < dl; k += 8) {
        const int e = elistS[k];
        const float2* eap = (const float2*)(ea + e * 6);
        const float2 a0 = eap[0], a1 = eap[1], a2 = eap[2];
        float d = bb;
        d = fmaf(a0.x, wv0.x, d); d = fmaf(a0.y, wv0.y, d);
        d = fmaf(a1.x, wv1.x, d); d = fmaf(a1.y, wv1.y, d);
        d = fmaf(a2.x, wv2.x, d); d = fmaf(a2.y, wv2.y, d);
        a = fmaf(x[ei[e]], fmaxf(d, 0.f), a);
    }
    partS[ech * 64 + ol] = a;
    __syncthreads();
    if (ech == 0) {
        float s = a;
#pragma unroll
        for (int p = 1; p < 8; p++) s += partS[p * 64 + ol];
        const float c = fmaxf((float)deg, 1.f);
        ws[OFF_X1 + n * 256 + o] = fmaxf(s / c + x[n] * lin1[o] + b1[o], 0.f);
    }
    if (och == 0) {
        if (tid < dl) ((int*)(ws + OFF_EL))[n * MAXE + tid] = elistS[tid];
        if (tid == 0) ws[OFF_CNT + n] = (float)deg;
    }
}

// ---------------- K2: dst-centric layer 2 -> x2[n, 16-o slice] -------------
__global__ __launch_bounds__(512) void x2_k(
    float* __restrict__ ws, const float* __restrict__ ea,
    const int* __restrict__ ei, const float* __restrict__ w2,
    const float* __restrict__ b2w, const float* __restrict__ lin2,
    const float* __restrict__ b2) {
    __shared__ float smem[11264];          // 45 KiB -> 3 blocks/CU
    float* xsS = smem;                     // 80*128 = 10240
    float* x1S = smem + 10240;             // 256
    float* easS = smem + 10496;            // 480
    int* srcS = (int*)(smem + 10976);      // 80
    int* elS = (int*)(smem + 11056);       // 80
    float* partA = smem;                   // alias xsS (used after compute)
    float* partB = smem + 512;
    __shared__ float cS;
    const int tid = threadIdx.x;
    const int n = blockIdx.x >> 4, og = blockIdx.x & 15;
    const int ol = tid & 15, ic = tid >> 4;   // 16 o-lanes x 32 i-chunks(4)
    const int o = og * 16 + ol;
    if (tid == 0) cS = ws[OFF_CNT + n];
    if (tid < MAXE) elS[tid] = ((const int*)(ws + OFF_EL))[n * MAXE + tid];
    if (tid >= 448) {
        const int q = tid - 448;
        *(float4*)&x1S[q * 4] = *(const float4*)(ws + OFF_X1 + n * 256 + q * 4);
    }
    __syncthreads();
    const int deg = (int)cS;
    const int dl = deg < MAXE ? deg : MAXE;
    if (tid < dl) {
        const int eid = elS[tid];
        srcS[tid] = ei[eid];
        const float2* eap = (const float2*)(ea + eid * 6);
        *(float2*)&easS[tid * 6] = eap[0];
        *(float2*)&easS[tid * 6 + 2] = eap[1];
        *(float2*)&easS[tid * 6 + 4] = eap[2];
    }
    float accm = 0.f;
    for (int p = 0; p < 2; ++p) {          // i-halves of 128
        __syncthreads();                   // srcS/easS ready; xs reusable
        for (int idx = tid; idx < dl * 32; idx += 512) {
            const int e = idx >> 5, ip = (idx & 31) * 4;
            *(float4*)&xsS[e * 128 + ip] =
                *(const float4*)(ws + OFF_X1 + srcS[e] * 256 + p * 128 + ip);
        }
        __syncthreads();
        const int i0 = p * 128 + ic * 4;
        const float* wp0 = w2 + (size_t)((i0 + 0) * 256 + o) * 6;
        const float* wp1 = w2 + (size_t)((i0 + 1) * 256 + o) * 6;
        const float* wp2 = w2 + (size_t)((i0 + 2) * 256 + o) * 6;
        const float* wp3 = w2 + (size_t)((i0 + 3) * 256 + o) * 6;
        const float2 wa0 = *(const float2*)wp0;
        const float2 wb0 = *(const float2*)(wp0 + 2);
        const float2 wc0 = *(const float2*)(wp0 + 4);
        const float2 wa1 = *(const float2*)wp1;
        const float2 wb1 = *(const float2*)(wp1 + 2);
        const float2 wc1 = *(const float2*)(wp1 + 4);
        const float2 wa2 = *(const float2*)wp2;
        const float2 wb2 = *(const float2*)(wp2 + 2);
        const float2 wc2 = *(const float2*)(wp2 + 4);
        const float2 wa3 = *(const float2*)wp3;
        const float2 wb3 = *(const float2*)(wp3 + 2);
        const float2 wc3 = *(const float2*)(wp3 + 4);
        const float bb0 = b2w[(i0 + 0) * 256 + o];
        const float bb1 = b2w[(i0 + 1) * 256 + o];
        const float bb2 = b2w[(i0 + 2) * 256 + o];
        const float bb3 = b2w[(i0 + 3) * 256 + o];
        for (int e = 0; e < dl; ++e) {
            const float2 e01 = *(const float2*)&easS[e * 6];
            const float2 e23 = *(const float2*)&easS[e * 6 + 2];
            const float2 e45 = *(const float2*)&easS[e * 6 + 4];
            const float4 xv = *(const float4*)&xsS[e * 128 + ic * 4];
            float d0 = bb0, d1 = bb1, d2 = bb2, d3 = bb3;
            d0 = fmaf(e01.x, wa0.x, d0); d1 = fmaf(e01.x, wa1.x, d1);
            d2 = fmaf(e01.x, wa2.x, d2); d3 = fmaf(e01.x, wa3.x, d3);
            d0 = fmaf(e01.y, wa0.y, d0); d1 = fmaf(e01.y, wa1.y, d1);
            d2 = fmaf(e01.y, wa2.y, d2); d3 = fmaf(e01.y, wa3.y, d3);
            d0 = fmaf(e23.x, wb0.x, d0); d1 = fmaf(e23.x, wb1.x, d1);
            d2 = fmaf(e23.x, wb2.x, d2); d3 = fmaf(e23.x, wb3.x, d3);
            d0 = fmaf(e23.y, wb0.y, d0); d1 = fmaf(e23.y, wb1.y, d1);
            d2 = fmaf(e23.y, wb2.y, d2); d3 = fmaf(e23.y, wb3.y, d3);
            d0 = fmaf(e45.x, wc0.x, d0); d1 = fmaf(e45.x, wc1.x, d1);
            d2 = fmaf(e45.x, wc2.x, d2); d3 = fmaf(e45.x, wc3.x, d3);
            d0 = fmaf(e45.y, wc0.y, d0); d1 = fmaf(e45.y, wc1.y, d1);
            d2 = fmaf(e45.y, wc2.y, d2); d3 = fmaf(e45.y, wc3.y, d3);
            d0 = fmaxf(d0, 0.f); d1 = fmaxf(d1, 0.f);
            d2 = fmaxf(d2, 0.f); d3 = fmaxf(d3, 0.f);
            accm = fmaf(xv.x, d0, accm);
            accm = fmaf(xv.y, d1, accm);
            accm = fmaf(xv.z, d2, accm);
            accm = fmaf(xv.w, d3, accm);
        }
    }
    // root (lin2) partial over this thread's 8 i's
    float accl = 0.f;
    {
        const float4 l0 = *(const float4*)(lin2 + (size_t)o * 256 + ic * 4);
        const float4 xa = *(const float4*)&x1S[ic * 4];
        accl = fmaf(l0.x, xa.x, accl); accl = fmaf(l0.y, xa.y, accl);
        accl = fmaf(l0.z, xa.z, accl); accl = fmaf(l0.w, xa.w, accl);
        const float4 l1 = *(const float4*)(lin2 + (size_t)o * 256 + 128 + ic * 4);
        const float4 xb = *(const float4*)&x1S[128 + ic * 4];
        accl = fmaf(l1.x, xb.x, accl); accl = fmaf(l1.y, xb.y, accl);
        accl = fmaf(l1.z, xb.z, accl); accl = fmaf(l1.w, xb.w, accl);
    }
    __syncthreads();                 // all xs reads done; partA aliases xsS
    partA[ic * 16 + ol] = accm;
    partB[ic * 16 + ol] = accl;
    __syncthreads();
    if (tid < 16) {
        float m = 0.f, l = 0.f;
        for (int k = 0; k < 32; ++k) {
            m += partA[k * 16 + tid];
            l += partB[k * 16 + tid];
        }
        const float c = fmaxf(cS, 1.f);
        ws[OFF_X2 + n * 256 + og * 16 + tid] =
            fmaxf(m / c + l + b2[og * 16 + tid], 0.f);
    }
}

// ---------- K3: dst-centric layer 3 -> x3[n, 16-o slice] (x2_k clone) ------
__global__ __launch_bounds__(512) void p3x3_k(
    float* __restrict__ ws, const float* __restrict__ ea,
    const int* __restrict__ ei, const float* __restrict__ w3,
    const float* __restrict__ b3w, const float* __restrict__ lin3,
    const float* __restrict__ b3) {
    __shared__ float smem[11264];          // 45 KiB
    float* xsS = smem;                     // 80*128 = 10240
    float* x2S = smem + 10240;             // 256
    float* easS = smem + 10496;            // 480
    int* srcS = (int*)(smem + 10976);      // 80
    int* elS = (int*)(smem + 11056);       // 80
    float* partA = smem;                   // alias xsS (used after compute)
    float* partB = smem + 512;
    __shared__ float cS;
    const int tid = threadIdx.x;
    const int n = blockIdx.x >> 2, og = blockIdx.x & 3;
    const int ol = tid & 15, ic = tid >> 4;   // 16 o-lanes x 32 i-chunks(4)
    const int o = og * 16 + ol;               // o in [0,64)
    if (tid == 0) cS = ws[OFF_CNT + n];
    if (tid < MAXE) elS[tid] = ((const int*)(ws + OFF_EL))[n * MAXE + tid];
    if (tid >= 448) {
        const int q = tid - 448;
        *(float4*)&x2S[q * 4] = *(const float4*)(ws + OFF_X2 + n * 256 + q * 4);
    }
    __syncthreads();
    const int deg = (int)cS;
    const int dl = deg < MAXE ? deg : MAXE;
    if (tid < dl) {
        const int eid = elS[tid];
        srcS[tid] = ei[eid];
        const float2* eap = (const float2*)(ea + eid * 6);
        *(float2*)&easS[tid * 6] = eap[0];
        *(float2*)&easS[tid * 6 + 2] = eap[1];
        *(float2*)&easS[tid * 6 + 4] = eap[2];
    }
    float accm = 0.f;
    for (int p = 0; p < 2; ++p) {          // i-halves of 128
        __syncthreads();
        for (int idx = tid; idx < dl * 32; idx += 512) {
            const int e = idx >> 5, ip = (idx & 31) * 4;
            *(float4*)&xsS[e * 128 + ip] =
                *(const float4*)(ws + OFF_X2 + srcS[e] * 256 + p * 128 + ip);
        }
        __syncthreads();
        const int i0 = p * 128 + ic * 4;
        const float* wp0 = w3 + (size_t)((i0 + 0) * 64 + o) * 6;
        const float* wp1 = w3 + (size_t)((i0 + 1) * 64 + o) * 6;
        const float* wp2 = w3 + (size_t)((i0 + 2) * 64 + o) * 6;
        const float* wp3 = w3 + (size_t)((i0 + 3) * 64 + o) * 6;
        const float2 wa0 = *(const float2*)wp0;
        const float2 wb0 = *(const float2*)(wp0 + 2);
        const float2 wc0 = *(const float2*)(wp0 + 4);
        const float2 wa1 = *(const float2*)wp1;
        const float2 wb1 = *(const float2*)(wp1 + 2);
        const float2 wc1 = *(const float2*)(wp1 + 4);
        const float2 wa2 = *(const float2*)wp2;
        const float2 wb2 = *(const float2*)(wp2 + 2);
        const float2 wc2 = *(const float2*)(wp2 + 4);
        const float2 wa3 = *(const float2*)wp3;
        const float2 wb3 = *(const float2*)(wp3 + 2);
        const float2 wc3 = *(const float2*)(wp3 + 4);
        const float bb0 = b3w[(i0 + 0) * 64 + o];
        const float bb1 = b3w[(i0 + 1) * 64 + o];
        const float bb2 = b3w[(i0 + 2) * 64 + o];
        const float bb3 = b3w[(i0 + 3) * 64 + o];
        for (int e = 0; e < dl; ++e) {
            const float2 e01 = *(const float2*)&easS[e * 6];
            const float2 e23 = *(const float2*)&easS[e * 6 + 2];
            const float2 e45 = *(const float2*)&easS[e * 6 + 4];
            const float4 xv = *(const float4*)&xsS[e * 128 + ic * 4];
            float d0 = bb0, d1 = bb1, d2 = bb2, d3 = bb3;
            d0 = fmaf(e01.x, wa0.x, d0); d1 = fmaf(e01.x, wa1.x, d1);
            d2 = fmaf(e01.x, wa2.x, d2); d3 = fmaf(e01.x, wa3.x, d3);
            d0 = fmaf(e01.y, wa0.y, d0); d1 = fmaf(e01.y, wa1.y, d1);
            d2 = fmaf(e01.y, wa2.y, d2); d3 = fmaf(e01.y, wa3.y, d3);
            d0 = fmaf(e23.x, wb0.x, d0); d1 = fmaf(e23.x, wb1.x, d1);
            d2 = fmaf(e23.x, wb2.x, d2); d3 = fmaf(e23.x, wb3.x, d3);
            d0 = fmaf(e23.y, wb0.y, d0); d1 = fmaf(e23.y, wb1.y, d1);
            d2 = fmaf(e23.y, wb2.y, d2); d3 = fmaf(e23.y, wb3.y, d3);
            d0 = fmaf(e45.x, wc0.x, d0); d1 = fmaf(e45.x, wc1.x, d1);
            d2 = fmaf(e45.x, wc2.x, d2); d3 = fmaf(e45.x, wc3.x, d3);
            d0 = fmaf(e45.y, wc0.y, d0); d1 = fmaf(e45.y, wc1.y, d1);
            d2 = fmaf(e45.y, wc2.y, d2); d3 = fmaf(e45.y, wc3.y, d3);
            d0 = fmaxf(d0, 0.f); d1 = fmaxf(d1, 0.f);
            d2 = fmaxf(d2, 0.f); d3 = fmaxf(d3, 0.f);
            accm = fmaf(xv.x, d0, accm);
            accm = fmaf(xv.y, d1, accm);
            accm = fmaf(xv.z, d2, accm);
            accm = fmaf(xv.w, d3, accm);
        }
    }
    // root (lin3) partial over this thread's 8 i's
    float accl = 0.f;
    {
        const float4 l0 = *(const float4*)(lin3 + (size_t)o * 256 + ic * 4);
        const float4 xa = *(const float4*)&x2S[ic * 4];
        accl = fmaf(l0.x, xa.x, accl); accl = fmaf(l0.y, xa.y, accl);
        accl = fmaf(l0.z, xa.z, accl); accl = fmaf(l0.w, xa.w, accl);
        const float4 l1 = *(const float4*)(lin3 + (size_t)o * 256 + 128 + ic * 4);
        const float4 xb = *(const float4*)&x2S[128 + ic * 4];
        accl = fmaf(l1.x, xb.x, accl); accl = fmaf(l1.y, xb.y, accl);
        accl = fmaf(l1.z, xb.z, accl); accl = fmaf(l1.w, xb.w, accl);
    }
    __syncthreads();                 // all xs reads done; partA aliases xsS
    partA[ic * 16 + ol] = accm;
    partB[ic * 16 + ol] = accl;
    __syncthreads();
    if (tid < 16) {
        float m = 0.f, l = 0.f;
        for (int k = 0; k < 32; ++k) {
            m += partA[k * 16 + tid];
            l += partB[k * 16 + tid];
        }
        const float c = fmaxf(cS, 1.f);
        ws[OFF_X3 + n * 64 + og * 16 + tid] =
            fmaxf(m / c + l + b3[og * 16 + tid], 0.f);
    }
}

// ---------------- K4: pairwise-L1 CBT --------------------------------------
__global__ __launch_bounds__(512) void cbt_k(const float* __restrict__ ws,
                                             float* __restrict__ out) {
    __shared__ float sx[NN * 64];
    const int tid = threadIdx.x;
    for (int idx = tid; idx < NN * 16; idx += 512)
        *(float4*)&sx[idx * 4] = *(const float4*)(ws + OFF_X3 + idx * 4);
    __syncthreads();
    const int f = tid & 63, jg = tid >> 6;
    const float xi = sx[blockIdx.x * 64 + f];
    for (int j = jg; j < NN; j += 8) {
        float d = fabsf(xi - sx[j * 64 + f]);
#pragma unroll
        for (int off = 32; off > 0; off >>= 1) d += __shfl_xor(d, off);
        if (f == 0) out[blockIdx.x * NN + j] = d;
    }
}

extern "C" void kernel_launch(void* const* d_in, const int* in_sizes, int n_in,
                              void* d_out, int out_size, void* d_ws, size_t ws_size,
                              hipStream_t stream) {
    (void)in_sizes; (void)n_in; (void)out_size; (void)ws_size;
    const float* x    = (const float*)d_in[0];
    const float* ea   = (const float*)d_in[1];
    const int*   ei   = (const int*)d_in[2];
    const float* nn1w = (const float*)d_in[3];
    const float* nn1b = (const float*)d_in[4];
    const float* lin1 = (const float*)d_in[5];
    const float* b1   = (const float*)d_in[6];
    const float* nn2w = (const float*)d_in[7];
    const float* nn2b = (const float*)d_in[8];
    const float* lin2 = (const float*)d_in[9];
    const float* b2   = (const float*)d_in[10];
    const float* nn3w = (const float*)d_in[11];
    const float* nn3b = (const float*)d_in[12];
    const float* lin3 = (const float*)d_in[13];
    const float* b3   = (const float*)d_in[14];

    float* ws = (float*)d_ws;
    x1_k<<<140, 512, 0, stream>>>(ws, x, ea, ei, nn1w, nn1b, lin1, b1);
    x2_k<<<NN * 16, 512, 0, stream>>>(ws, ea, ei, nn2w, nn2b, lin2, b2);
    p3x3_k<<<NN * 4, 512, 0, stream>>>(ws, ea, ei, nn3w, nn3b, lin3, b3);
    cbt_k<<<NN, 512, 0, stream>>>(ws, (float*)d_out);
}